// Round 13
// baseline (2140.848 us; speedup 1.0000x reference)
//
#include <hip/hip_runtime.h>
#include <math.h>

// ---------------------------------------------------------------------------
// GCN 5-layer forward, dinv-prescaled formulation.
//   agg[v] = dinv[v] * ( sum_{s in N(v)} hs[s] + hs[v] ),  hs = dinv (.) h.
// Layer plan (narrow-side aggregation):
//   L1: agg2(xs=dinv*x) -> gemm 2->128 +b1 relu *dinv
//   L2: gemm_big128 128->128 ; agg128 +b2 relu *dinv
//   L3: gemm 128->32  ; agg32  +b3 relu *dinv
//   L4: gemm 32->32   ; agg32  +b4 relu *dinv
//   L5: agg32 raw     ; gemm_final: (t5@W5+b5).relu @ Wl + bl -> out
// Structural walls (measured): agg128 ~127us (FETCH=414MB = per-XCD L2-miss
//   fabric fill ~0.4 TB/s/XCD; invariant across R3-R12 shapes). agg32 trio
//   ~40-45us each (12.8MB working set >> 4MB per-XCD L2, same wall).
// R13: L2 GEMM was LDS-BW bound (1.5 B/FMA = 2.25x FMA issue rate -> ~47us).
//   New gemm_big128: 128x128 tile, 8 rows x 8 cols per thread -> 1.0 B/FMA
//   (LDS/FMA 1.5x) -> ~31us floor. Rows strided (tr + 16*r) to spread LDS
//   banks; unroll 1 everywhere to pin VGPR (~112 < 128 cap, no spill).
// ---------------------------------------------------------------------------

static inline int cdiv(int a, int b) { return (a + b - 1) / b; }

__global__ void zero_i32(int* __restrict__ p, int n) {
    int i = blockIdx.x * 256 + threadIdx.x;
    if (i < n) p[i] = 0;
}

// Plain 1-pass degree count: atomics, no line-ownership migration.
__global__ void count_kernel(const int* __restrict__ dst, int* __restrict__ cnt, int E) {
    int e = blockIdx.x * 256 + threadIdx.x;
    if (e < E) atomicAdd(&cnt[dst[e]], 1);
}

// Inclusive scan per 256-block; inclusive partials to off, block totals to bsum.
__global__ void scan1(const int* __restrict__ cnt, int* __restrict__ off,
                      int* __restrict__ bsum, int n) {
    __shared__ int sm[256];
    int i = blockIdx.x * 256 + threadIdx.x;
    int v = (i < n) ? cnt[i] : 0;
    sm[threadIdx.x] = v;
    __syncthreads();
    for (int ofs = 1; ofs < 256; ofs <<= 1) {
        int t = (threadIdx.x >= (unsigned)ofs) ? sm[threadIdx.x - ofs] : 0;
        __syncthreads();
        sm[threadIdx.x] += t;
        __syncthreads();
    }
    if (i < n) off[i] = sm[threadIdx.x];
    if (threadIdx.x == 255) bsum[blockIdx.x] = sm[255];
}

// Exclusive scan of block sums (nb <= 512).
__global__ void scan2(const int* __restrict__ bsum, int* __restrict__ bpre,
                      int nb, int* __restrict__ off, int N, int E) {
    __shared__ int sm[512];
    int t = threadIdx.x;
    sm[t] = (t < nb) ? bsum[t] : 0;
    __syncthreads();
    for (int ofs = 1; ofs < 512; ofs <<= 1) {
        int v = (t >= ofs) ? sm[t - ofs] : 0;
        __syncthreads();
        sm[t] += v;
        __syncthreads();
    }
    if (t < nb) bpre[t] = sm[t] - bsum[t];
    if (t == 0) off[N] = E;
}

// Fused: finalize off (exclusive), seed cursor=off, dinv=1/sqrt(deg+1),
// xs = dinv * x (pre-scaled layer-1 input).
__global__ void scan3_fused(const int* __restrict__ cnt, const int* __restrict__ bpre,
                            int* __restrict__ off, int* __restrict__ cursor,
                            const float* __restrict__ x, float* __restrict__ dinv,
                            float* __restrict__ xs, int n) {
    int i = blockIdx.x * 256 + threadIdx.x;
    if (i < n) {
        int c = cnt[i];
        int o = off[i] - c + bpre[blockIdx.x];
        off[i] = o;
        cursor[i] = o;
        float dv = 1.0f / sqrtf((float)c + 1.0f);
        dinv[i] = dv;
        float2 xv = *reinterpret_cast<const float2*>(x + 2 * (size_t)i);
        *reinterpret_cast<float2*>(xs + 2 * (size_t)i) = float2{dv * xv.x, dv * xv.y};
    }
}

// XCD-class-filtered CSR fill: class c handles only its dst-range, so its
// cursor slice (~50 KB) and csr slice (~800 KB) stay in one XCD's L2.
// (Stores DO need single-writer-XCD locality; see R8.)
__global__ __launch_bounds__(256) void fill_ranged(const int* __restrict__ src,
                                                   const int* __restrict__ dst,
                                                   int* __restrict__ cursor,
                                                   int* __restrict__ csr,
                                                   int E, int N, int echunk) {
    int cls = blockIdx.x & 7;
    int chunk = blockIdx.x >> 3;
    int per = (N + 7) >> 3;
    int lo = cls * per;
    int hi = lo + per; if (hi > N) hi = N;
    int e0 = chunk * echunk;
    int e1 = e0 + echunk; if (e1 > E) e1 = E;
    for (int e = e0 + (int)threadIdx.x; e < e1; e += 256) {
        int d = dst[e];
        if (d >= lo && d < hi) {
            int p = atomicAdd(&cursor[d], 1);
            csr[p] = src[e];
        }
    }
}

// ---------------------------------------------------------------------------
// Aggregation of pre-scaled [N,2] input: one thread per node.
// ---------------------------------------------------------------------------
__global__ __launch_bounds__(256) void agg2_kernel(const float* __restrict__ xs,
                                                   const int* __restrict__ off,
                                                   const int* __restrict__ csr,
                                                   const float* __restrict__ dinv,
                                                   float* __restrict__ out, int n) {
    int v = blockIdx.x * 256 + threadIdx.x;
    if (v >= n) return;
    float a0 = 0.f, a1 = 0.f;
    int e0 = off[v], e1 = off[v + 1];
    for (int e = e0; e < e1; e++) {
        int s = csr[e];
        float2 q = *reinterpret_cast<const float2*>(xs + 2 * (size_t)s);
        a0 += q.x;
        a1 += q.y;
    }
    float dv = dinv[v];
    float2 xv = *reinterpret_cast<const float2*>(xs + 2 * (size_t)v);
    *reinterpret_cast<float2*>(out + 2 * (size_t)v) =
        float2{dv * (a0 + xv.x), dv * (a1 + xv.y)};
}

// ---------------------------------------------------------------------------
// agg128: F=128, 16 lanes/node, each lane owns 8 cols (2 x float4).
// ---------------------------------------------------------------------------
template <bool BR, bool PS>
__global__ __launch_bounds__(256) void agg128_kernel(const float* __restrict__ h,
                                                     const int* __restrict__ off,
                                                     const int* __restrict__ csr,
                                                     const float* __restrict__ dinv,
                                                     const float* __restrict__ bias,
                                                     float* __restrict__ out, int n) {
    int tid = threadIdx.x;
    int lane = tid & 63;
    int sl = lane & 15;
    int subbase = lane & ~15;
    int wave = tid >> 6;
    int v = blockIdx.x * 16 + wave * 4 + (lane >> 4);
    if (v >= n) return;

    int start = off[v];
    int end = off[v + 1];

    float4 accA = {0.f, 0.f, 0.f, 0.f};
    float4 accB = {0.f, 0.f, 0.f, 0.f};

    for (int base = start; base < end; base += 16) {
        int m = end - base;
        if (m > 16) m = 16;
        int idx = (sl < m) ? csr[base + sl] : 0;
        int i = 0;
        for (; i + 8 <= m; i += 8) {
            float4 ha[8], hb[8];
#pragma unroll
            for (int u = 0; u < 8; u++) {
                int s = __shfl(idx, subbase + i + u);
                const float* p = h + (size_t)s * 128 + sl * 8;
                ha[u] = *reinterpret_cast<const float4*>(p);
                hb[u] = *reinterpret_cast<const float4*>(p + 4);
            }
#pragma unroll
            for (int u = 0; u < 8; u++) {
                accA.x += ha[u].x; accA.y += ha[u].y; accA.z += ha[u].z; accA.w += ha[u].w;
                accB.x += hb[u].x; accB.y += hb[u].y; accB.z += hb[u].z; accB.w += hb[u].w;
            }
        }
        if (i + 4 <= m) {
            float4 ha[4], hb[4];
#pragma unroll
            for (int u = 0; u < 4; u++) {
                int s = __shfl(idx, subbase + i + u);
                const float* p = h + (size_t)s * 128 + sl * 8;
                ha[u] = *reinterpret_cast<const float4*>(p);
                hb[u] = *reinterpret_cast<const float4*>(p + 4);
            }
#pragma unroll
            for (int u = 0; u < 4; u++) {
                accA.x += ha[u].x; accA.y += ha[u].y; accA.z += ha[u].z; accA.w += ha[u].w;
                accB.x += hb[u].x; accB.y += hb[u].y; accB.z += hb[u].z; accB.w += hb[u].w;
            }
            i += 4;
        }
        if (i + 2 <= m) {
            int s0 = __shfl(idx, subbase + i);
            int s1 = __shfl(idx, subbase + i + 1);
            const float* p0 = h + (size_t)s0 * 128 + sl * 8;
            const float* p1 = h + (size_t)s1 * 128 + sl * 8;
            float4 a0 = *reinterpret_cast<const float4*>(p0);
            float4 b0 = *reinterpret_cast<const float4*>(p0 + 4);
            float4 a1 = *reinterpret_cast<const float4*>(p1);
            float4 b1 = *reinterpret_cast<const float4*>(p1 + 4);
            accA.x += a0.x + a1.x; accA.y += a0.y + a1.y;
            accA.z += a0.z + a1.z; accA.w += a0.w + a1.w;
            accB.x += b0.x + b1.x; accB.y += b0.y + b1.y;
            accB.z += b0.z + b1.z; accB.w += b0.w + b1.w;
            i += 2;
        }
        if (i < m) {
            int s0 = __shfl(idx, subbase + i);
            const float* p0 = h + (size_t)s0 * 128 + sl * 8;
            float4 a0 = *reinterpret_cast<const float4*>(p0);
            float4 b0 = *reinterpret_cast<const float4*>(p0 + 4);
            accA.x += a0.x; accA.y += a0.y; accA.z += a0.z; accA.w += a0.w;
            accB.x += b0.x; accB.y += b0.y; accB.z += b0.z; accB.w += b0.w;
        }
    }

    float dv = dinv[v];
    const float* pv = h + (size_t)v * 128 + sl * 8;
    float4 hvA = *reinterpret_cast<const float4*>(pv);
    float4 hvB = *reinterpret_cast<const float4*>(pv + 4);
    float4 oA, oB;
    oA.x = dv * (accA.x + hvA.x); oA.y = dv * (accA.y + hvA.y);
    oA.z = dv * (accA.z + hvA.z); oA.w = dv * (accA.w + hvA.w);
    oB.x = dv * (accB.x + hvB.x); oB.y = dv * (accB.y + hvB.y);
    oB.z = dv * (accB.z + hvB.z); oB.w = dv * (accB.w + hvB.w);
    if constexpr (BR) {
        float4 bA = *reinterpret_cast<const float4*>(bias + sl * 8);
        float4 bB = *reinterpret_cast<const float4*>(bias + sl * 8 + 4);
        oA.x = fmaxf(oA.x + bA.x, 0.f); oA.y = fmaxf(oA.y + bA.y, 0.f);
        oA.z = fmaxf(oA.z + bA.z, 0.f); oA.w = fmaxf(oA.w + bA.w, 0.f);
        oB.x = fmaxf(oB.x + bB.x, 0.f); oB.y = fmaxf(oB.y + bB.y, 0.f);
        oB.z = fmaxf(oB.z + bB.z, 0.f); oB.w = fmaxf(oB.w + bB.w, 0.f);
    }
    if constexpr (PS) {
        oA.x *= dv; oA.y *= dv; oA.z *= dv; oA.w *= dv;
        oB.x *= dv; oB.y *= dv; oB.z *= dv; oB.w *= dv;
    }
    float* po = out + (size_t)v * 128 + sl * 8;
    *reinterpret_cast<float4*>(po) = oA;
    *reinterpret_cast<float4*>(po + 4) = oB;
}

// ---------------------------------------------------------------------------
// agg32: F=32, 8 lanes/node, lane owns 4 cols (float4). Dual 8-edge chunks.
// ---------------------------------------------------------------------------
template <bool BR, bool PS>
__global__ __launch_bounds__(256) void agg32_kernel(const float* __restrict__ h,
                                                    const int* __restrict__ off,
                                                    const int* __restrict__ csr,
                                                    const float* __restrict__ dinv,
                                                    const float* __restrict__ bias,
                                                    float* __restrict__ out, int n) {
    int tid = threadIdx.x;
    int lane = tid & 63;
    int sl = lane & 7;
    int subbase = lane & ~7;
    int wave = tid >> 6;
    int v = blockIdx.x * 32 + wave * 8 + (lane >> 3);
    if (v >= n) return;

    int start = off[v];
    int end = off[v + 1];

    float4 acc = {0.f, 0.f, 0.f, 0.f};

    for (int base = start; base < end; base += 16) {
        int m = end - base;
        if (m > 16) m = 16;
        int idxA = (sl < m) ? csr[base + sl] : 0;
        int idxB = (8 + sl < m) ? csr[base + 8 + sl] : 0;
        if (m == 16) {
            float4 hb[16];
#pragma unroll
            for (int u = 0; u < 16; u++) {
                int s = __shfl((u < 8) ? idxA : idxB, subbase + (u & 7));
                hb[u] = *reinterpret_cast<const float4*>(h + (size_t)s * 32 + sl * 4);
            }
#pragma unroll
            for (int u = 0; u < 16; u++) {
                acc.x += hb[u].x; acc.y += hb[u].y; acc.z += hb[u].z; acc.w += hb[u].w;
            }
        } else {
            int ma = (m < 8) ? m : 8;
            int i = 0;
            for (; i + 4 <= ma; i += 4) {
                float4 hb[4];
#pragma unroll
                for (int u = 0; u < 4; u++) {
                    int s = __shfl(idxA, subbase + i + u);
                    hb[u] = *reinterpret_cast<const float4*>(h + (size_t)s * 32 + sl * 4);
                }
#pragma unroll
                for (int u = 0; u < 4; u++) {
                    acc.x += hb[u].x; acc.y += hb[u].y; acc.z += hb[u].z; acc.w += hb[u].w;
                }
            }
            if (i + 2 <= ma) {
                int s0 = __shfl(idxA, subbase + i);
                int s1 = __shfl(idxA, subbase + i + 1);
                float4 h0 = *reinterpret_cast<const float4*>(h + (size_t)s0 * 32 + sl * 4);
                float4 h1 = *reinterpret_cast<const float4*>(h + (size_t)s1 * 32 + sl * 4);
                acc.x += h0.x + h1.x; acc.y += h0.y + h1.y;
                acc.z += h0.z + h1.z; acc.w += h0.w + h1.w;
                i += 2;
            }
            if (i < ma) {
                int s0 = __shfl(idxA, subbase + i);
                float4 h0 = *reinterpret_cast<const float4*>(h + (size_t)s0 * 32 + sl * 4);
                acc.x += h0.x; acc.y += h0.y; acc.z += h0.z; acc.w += h0.w;
            }
            if (m > 8) {
                int mb = m - 8;
                int j = 0;
                for (; j + 4 <= mb; j += 4) {
                    float4 hb[4];
#pragma unroll
                    for (int u = 0; u < 4; u++) {
                        int s = __shfl(idxB, subbase + j + u);
                        hb[u] = *reinterpret_cast<const float4*>(h + (size_t)s * 32 + sl * 4);
                    }
#pragma unroll
                    for (int u = 0; u < 4; u++) {
                        acc.x += hb[u].x; acc.y += hb[u].y; acc.z += hb[u].z; acc.w += hb[u].w;
                    }
                }
                if (j + 2 <= mb) {
                    int s0 = __shfl(idxB, subbase + j);
                    int s1 = __shfl(idxB, subbase + j + 1);
                    float4 h0 = *reinterpret_cast<const float4*>(h + (size_t)s0 * 32 + sl * 4);
                    float4 h1 = *reinterpret_cast<const float4*>(h + (size_t)s1 * 32 + sl * 4);
                    acc.x += h0.x + h1.x; acc.y += h0.y + h1.y;
                    acc.z += h0.z + h1.z; acc.w += h0.w + h1.w;
                    j += 2;
                }
                if (j < mb) {
                    int s0 = __shfl(idxB, subbase + j);
                    float4 h0 = *reinterpret_cast<const float4*>(h + (size_t)s0 * 32 + sl * 4);
                    acc.x += h0.x; acc.y += h0.y; acc.z += h0.z; acc.w += h0.w;
                }
            }
        }
    }

    float dv = dinv[v];
    float4 hv = *reinterpret_cast<const float4*>(h + (size_t)v * 32 + sl * 4);
    float o0 = dv * (acc.x + hv.x);
    float o1 = dv * (acc.y + hv.y);
    float o2 = dv * (acc.z + hv.z);
    float o3 = dv * (acc.w + hv.w);
    if constexpr (BR) {
        float4 b = *reinterpret_cast<const float4*>(bias + sl * 4);
        o0 = fmaxf(o0 + b.x, 0.f);
        o1 = fmaxf(o1 + b.y, 0.f);
        o2 = fmaxf(o2 + b.z, 0.f);
        o3 = fmaxf(o3 + b.w, 0.f);
    }
    if constexpr (PS) {
        o0 *= dv; o1 *= dv; o2 *= dv; o3 *= dv;
    }
    *reinterpret_cast<float4*>(out + (size_t)v * 32 + sl * 4) = float4{o0, o1, o2, o3};
}

// ---------------------------------------------------------------------------
// gemm_big128: h[N,128] = x[N,K] @ W[K,128]. 128x128 block tile, 256 threads,
// thread owns 8 rows (strided: tr + 16*r) x 8 cols -> 1.0 B-of-LDS/FMA.
// Registers: acc 64 + w 32 + misc ~= 112 < 128 cap (launch_bounds 256,4).
// ---------------------------------------------------------------------------
template <int K, bool BR, bool PS>
__global__ __launch_bounds__(256, 4) void gemm_big128(const float* __restrict__ x,
                                                      const float* __restrict__ W,
                                                      const float* __restrict__ bias,
                                                      const float* __restrict__ dinv,
                                                      float* __restrict__ h, int n) {
    constexpr int F = 128;
    constexpr int KC = 32;
    constexpr int KCP = 36;             // padded row stride (16B-aligned)
    constexpr int ROWS = 128;
    static_assert(K % KC == 0, "K must be a multiple of 32");

    __shared__ float Ws[KC * F];        // 16 KB
    __shared__ float Xs[ROWS * KCP];    // 18.4 KB

    const int tid = threadIdx.x;
    const int cb = (tid & 15) * 8;      // col base (8 cols)
    const int tr = tid >> 4;            // 0..15; rows tr + 16*r
    const int row0 = blockIdx.x * ROWS;

    float4 acc0[8], acc1[8];
#pragma unroll
    for (int r = 0; r < 8; r++) {
        acc0[r] = float4{0.f, 0.f, 0.f, 0.f};
        acc1[r] = float4{0.f, 0.f, 0.f, 0.f};
    }

#pragma unroll 1
    for (int k0 = 0; k0 < K; k0 += KC) {
        __syncthreads();
        {
            // Stage X chunk: 128 rows x 32 cols; thread -> row tid>>1, 16 cols.
            int r = tid >> 1;
            int kk = (tid & 1) * 16;
            int gr = row0 + r;
            float4 v0 = {0,0,0,0}, v1 = {0,0,0,0}, v2 = {0,0,0,0}, v3 = {0,0,0,0};
            if (gr < n) {
                const float* p = x + (size_t)gr * K + k0 + kk;
                v0 = *reinterpret_cast<const float4*>(p);
                v1 = *reinterpret_cast<const float4*>(p + 4);
                v2 = *reinterpret_cast<const float4*>(p + 8);
                v3 = *reinterpret_cast<const float4*>(p + 12);
            }
            float* q = &Xs[r * KCP + kk];
            *reinterpret_cast<float4*>(q) = v0;
            *reinterpret_cast<float4*>(q + 4) = v1;
            *reinterpret_cast<float4*>(q + 8) = v2;
            *reinterpret_cast<float4*>(q + 12) = v3;
        }
        for (int i = tid; i < KC * F / 4; i += 256) {
            *reinterpret_cast<float4*>(&Ws[i * 4]) =
                *reinterpret_cast<const float4*>(W + (size_t)k0 * F + i * 4);
        }
        __syncthreads();

#pragma unroll 1
        for (int kk4 = 0; kk4 < KC; kk4 += 4) {
            float4 w0[4], w1[4];
#pragma unroll
            for (int j = 0; j < 4; j++) {
                w0[j] = *reinterpret_cast<const float4*>(&Ws[(kk4 + j) * F + cb]);
                w1[j] = *reinterpret_cast<const float4*>(&Ws[(kk4 + j) * F + cb + 4]);
            }
#pragma unroll
            for (int r = 0; r < 8; r++) {
                float4 xv = *reinterpret_cast<const float4*>(&Xs[(tr + 16 * r) * KCP + kk4]);
                acc0[r].x += xv.x * w0[0].x; acc0[r].y += xv.x * w0[0].y;
                acc0[r].z += xv.x * w0[0].z; acc0[r].w += xv.x * w0[0].w;
                acc1[r].x += xv.x * w1[0].x; acc1[r].y += xv.x * w1[0].y;
                acc1[r].z += xv.x * w1[0].z; acc1[r].w += xv.x * w1[0].w;
                acc0[r].x += xv.y * w0[1].x; acc0[r].y += xv.y * w0[1].y;
                acc0[r].z += xv.y * w0[1].z; acc0[r].w += xv.y * w0[1].w;
                acc1[r].x += xv.y * w1[1].x; acc1[r].y += xv.y * w1[1].y;
                acc1[r].z += xv.y * w1[1].z; acc1[r].w += xv.y * w1[1].w;
                acc0[r].x += xv.z * w0[2].x; acc0[r].y += xv.z * w0[2].y;
                acc0[r].z += xv.z * w0[2].z; acc0[r].w += xv.z * w0[2].w;
                acc1[r].x += xv.z * w1[2].x; acc1[r].y += xv.z * w1[2].y;
                acc1[r].z += xv.z * w1[2].z; acc1[r].w += xv.z * w1[2].w;
                acc0[r].x += xv.w * w0[3].x; acc0[r].y += xv.w * w0[3].y;
                acc0[r].z += xv.w * w0[3].z; acc0[r].w += xv.w * w0[3].w;
                acc1[r].x += xv.w * w1[3].x; acc1[r].y += xv.w * w1[3].y;
                acc1[r].z += xv.w * w1[3].z; acc1[r].w += xv.w * w1[3].w;
            }
        }
    }

    float4 b0 = {0,0,0,0}, b1 = {0,0,0,0};
    if constexpr (BR) {
        b0 = *reinterpret_cast<const float4*>(bias + cb);
        b1 = *reinterpret_cast<const float4*>(bias + cb + 4);
    }
#pragma unroll
    for (int r = 0; r < 8; r++) {
        int row = row0 + tr + 16 * r;
        if (row < n) {
            float4 oA = acc0[r], oB = acc1[r];
            if constexpr (BR) {
                oA.x = fmaxf(oA.x + b0.x, 0.f); oA.y = fmaxf(oA.y + b0.y, 0.f);
                oA.z = fmaxf(oA.z + b0.z, 0.f); oA.w = fmaxf(oA.w + b0.w, 0.f);
                oB.x = fmaxf(oB.x + b1.x, 0.f); oB.y = fmaxf(oB.y + b1.y, 0.f);
                oB.z = fmaxf(oB.z + b1.z, 0.f); oB.w = fmaxf(oB.w + b1.w, 0.f);
            }
            if constexpr (PS) {
                float dv = dinv[row];
                oA.x *= dv; oA.y *= dv; oA.z *= dv; oA.w *= dv;
                oB.x *= dv; oB.y *= dv; oB.z *= dv; oB.w *= dv;
            }
            float* p = &h[(size_t)row * F + cb];
            *reinterpret_cast<float4*>(p) = oA;
            *reinterpret_cast<float4*>(p + 4) = oB;
        }
    }
}

// ---------------------------------------------------------------------------
// Register-tiled GEMM (F=32/64 paths): h[N,F] = x[N,K] @ W[K,F].
// KC=32 (KCP=36): K=128 -> 4 chunks, K=32 -> single chunk.
// ---------------------------------------------------------------------------
template <int K, int F, bool BR, bool PS>
__global__ __launch_bounds__(256, 4) void gemm_tiled(const float* __restrict__ x,
                                                     const float* __restrict__ W,
                                                     const float* __restrict__ bias,
                                                     const float* __restrict__ dinv,
                                                     float* __restrict__ h, int n) {
    constexpr int KC = 32;
    constexpr int KCP = 36;
    constexpr int ROWS = 64;
    constexpr int TPC = F / 4;
    constexpr int RT = 256 / TPC;
    constexpr int RPT = ROWS / RT;
    static_assert(K % KC == 0, "K must be a multiple of 32");

    __shared__ float Ws[KC * F];
    __shared__ float Xs[ROWS * KCP];

    const int tid = threadIdx.x;
    const int cb = (tid % TPC) * 4;
    const int tr = tid / TPC;
    const int row0 = blockIdx.x * ROWS;

    float acc[RPT][4];
#pragma unroll
    for (int r = 0; r < RPT; r++)
#pragma unroll
        for (int j = 0; j < 4; j++) acc[r][j] = 0.f;

#pragma unroll 1
    for (int k0 = 0; k0 < K; k0 += KC) {
        __syncthreads();
        {
            int r = tid >> 2;
            int kk = (tid & 3) * 8;
            int gr = row0 + r;
            float4 v0 = {0.f, 0.f, 0.f, 0.f}, v1 = {0.f, 0.f, 0.f, 0.f};
            if (gr < n) {
                v0 = *reinterpret_cast<const float4*>(x + (size_t)gr * K + k0 + kk);
                v1 = *reinterpret_cast<const float4*>(x + (size_t)gr * K + k0 + kk + 4);
            }
            *reinterpret_cast<float4*>(&Xs[r * KCP + kk]) = v0;
            *reinterpret_cast<float4*>(&Xs[r * KCP + kk + 4]) = v1;
        }
        for (int i = tid; i < KC * F / 4; i += 256) {
            *reinterpret_cast<float4*>(&Ws[i * 4]) =
                *reinterpret_cast<const float4*>(W + (size_t)k0 * F + i * 4);
        }
        __syncthreads();

#pragma unroll 4
        for (int kk4 = 0; kk4 < KC; kk4 += 4) {
            float4 xr[RPT];
#pragma unroll
            for (int r = 0; r < RPT; r++)
                xr[r] = *reinterpret_cast<const float4*>(&Xs[(tr * RPT + r) * KCP + kk4]);
#pragma unroll
            for (int j = 0; j < 4; j++) {
                float4 w = *reinterpret_cast<const float4*>(&Ws[(kk4 + j) * F + cb]);
#pragma unroll
                for (int r = 0; r < RPT; r++) {
                    float xv = (j == 0) ? xr[r].x : (j == 1) ? xr[r].y
                             : (j == 2) ? xr[r].z : xr[r].w;
                    acc[r][0] += xv * w.x;
                    acc[r][1] += xv * w.y;
                    acc[r][2] += xv * w.z;
                    acc[r][3] += xv * w.w;
                }
            }
        }
    }

    float4 b = float4{0.f, 0.f, 0.f, 0.f};
    if constexpr (BR) b = *reinterpret_cast<const float4*>(bias + cb);
#pragma unroll
    for (int r = 0; r < RPT; r++) {
        int row = row0 + tr * RPT + r;
        if (row < n) {
            float o0 = acc[r][0], o1 = acc[r][1], o2 = acc[r][2], o3 = acc[r][3];
            if constexpr (BR) {
                o0 = fmaxf(o0 + b.x, 0.f);
                o1 = fmaxf(o1 + b.y, 0.f);
                o2 = fmaxf(o2 + b.z, 0.f);
                o3 = fmaxf(o3 + b.w, 0.f);
            }
            if constexpr (PS) {
                float dv = dinv[row];
                o0 *= dv; o1 *= dv; o2 *= dv; o3 *= dv;
            }
            *reinterpret_cast<float4*>(&h[(size_t)row * F + cb]) = float4{o0, o1, o2, o3};
        }
    }
}

// ---------------------------------------------------------------------------
// Fused L5 + final: out[v] = relu(t5[v]@W5 + b5) . Wl + bl.  K=32, F=64.
// ---------------------------------------------------------------------------
__global__ __launch_bounds__(256, 4) void gemm_final(const float* __restrict__ x,
                                                     const float* __restrict__ W,
                                                     const float* __restrict__ bias,
                                                     const float* __restrict__ Wl,
                                                     const float* __restrict__ bl,
                                                     float* __restrict__ out, int n) {
    constexpr int K = 32, F = 64;
    constexpr int KC = 32;
    constexpr int KCP = 36;
    constexpr int ROWS = 64;
    constexpr int TPC = F / 4;          // 16
    constexpr int RT = 256 / TPC;       // 16
    constexpr int RPT = ROWS / RT;      // 4

    __shared__ float Ws[KC * F];
    __shared__ float Xs[ROWS * KCP];
    __shared__ float wl[F];

    const int tid = threadIdx.x;
    if (tid < F) wl[tid] = Wl[tid];
    const int cb = (tid % TPC) * 4;
    const int tr = tid / TPC;
    const int row0 = blockIdx.x * ROWS;

    float acc[RPT][4];
#pragma unroll
    for (int r = 0; r < RPT; r++)
#pragma unroll
        for (int j = 0; j < 4; j++) acc[r][j] = 0.f;

    {
        {
            int r = tid >> 2;
            int kk = (tid & 3) * 8;
            int gr = row0 + r;
            float4 v0 = {0.f, 0.f, 0.f, 0.f}, v1 = {0.f, 0.f, 0.f, 0.f};
            if (gr < n) {
                v0 = *reinterpret_cast<const float4*>(x + (size_t)gr * K + kk);
                v1 = *reinterpret_cast<const float4*>(x + (size_t)gr * K + kk + 4);
            }
            *reinterpret_cast<float4*>(&Xs[r * KCP + kk]) = v0;
            *reinterpret_cast<float4*>(&Xs[r * KCP + kk + 4]) = v1;
        }
        for (int i = tid; i < KC * F / 4; i += 256) {
            *reinterpret_cast<float4*>(&Ws[i * 4]) =
                *reinterpret_cast<const float4*>(W + i * 4);
        }
        __syncthreads();

#pragma unroll 4
        for (int kk4 = 0; kk4 < KC; kk4 += 4) {
            float4 xr[RPT];
#pragma unroll
            for (int r = 0; r < RPT; r++)
                xr[r] = *reinterpret_cast<const float4*>(&Xs[(tr * RPT + r) * KCP + kk4]);
#pragma unroll
            for (int j = 0; j < 4; j++) {
                float4 w = *reinterpret_cast<const float4*>(&Ws[(kk4 + j) * F + cb]);
#pragma unroll
                for (int r = 0; r < RPT; r++) {
                    float xv = (j == 0) ? xr[r].x : (j == 1) ? xr[r].y
                             : (j == 2) ? xr[r].z : xr[r].w;
                    acc[r][0] += xv * w.x;
                    acc[r][1] += xv * w.y;
                    acc[r][2] += xv * w.z;
                    acc[r][3] += xv * w.w;
                }
            }
        }
    }

    float4 b = *reinterpret_cast<const float4*>(bias + cb);
    float4 w = *reinterpret_cast<const float4*>(&wl[cb]);
    float blv = bl[0];
#pragma unroll
    for (int r = 0; r < RPT; r++) {
        int row = row0 + tr * RPT + r;
        float o0 = fmaxf(acc[r][0] + b.x, 0.f);
        float o1 = fmaxf(acc[r][1] + b.y, 0.f);
        float o2 = fmaxf(acc[r][2] + b.z, 0.f);
        float o3 = fmaxf(acc[r][3] + b.w, 0.f);
        float partial = o0 * w.x + o1 * w.y + o2 * w.z + o3 * w.w;
        partial += __shfl_xor(partial, 8, 16);
        partial += __shfl_xor(partial, 4, 16);
        partial += __shfl_xor(partial, 2, 16);
        partial += __shfl_xor(partial, 1, 16);
        if ((tid & 15) == 0 && row < n) out[row] = partial + blv;
    }
}

// Simple GEMM for K=2 (layer 1), epilogue +bias/relu (BR), *dinv (PS).
template <int K, int F, bool BR, bool PS>
__global__ __launch_bounds__(256, 4) void gemm_small(const float* __restrict__ x,
                                                     const float* __restrict__ W,
                                                     const float* __restrict__ bias,
                                                     const float* __restrict__ dinv,
                                                     float* __restrict__ h, int n) {
    constexpr int TPR = F / 4;
    constexpr int ROWS = 256 / TPR;
    __shared__ float Ws[K * F];
    for (int i = threadIdx.x; i < K * F; i += 256) Ws[i] = W[i];
    __syncthreads();

    int tid = threadIdx.x;
    int cb = (tid % TPR) * 4;
    int r = blockIdx.x * ROWS + tid / TPR;
    if (r >= n) return;

    const float* xr = x + (size_t)r * K;
    float a0 = 0.f, a1 = 0.f, a2 = 0.f, a3 = 0.f;
#pragma unroll
    for (int k = 0; k < K; k++) {
        float xv = xr[k];
        float4 w = *reinterpret_cast<const float4*>(&Ws[k * F + cb]);
        a0 += xv * w.x; a1 += xv * w.y; a2 += xv * w.z; a3 += xv * w.w;
    }
    if constexpr (BR) {
        float4 b = *reinterpret_cast<const float4*>(bias + cb);
        a0 = fmaxf(a0 + b.x, 0.f);
        a1 = fmaxf(a1 + b.y, 0.f);
        a2 = fmaxf(a2 + b.z, 0.f);
        a3 = fmaxf(a3 + b.w, 0.f);
    }
    if constexpr (PS) {
        float dv = dinv[r];
        a0 *= dv; a1 *= dv; a2 *= dv; a3 *= dv;
    }
    *reinterpret_cast<float4*>(&h[(size_t)r * F + cb]) = float4{a0, a1, a2, a3};
}

extern "C" void kernel_launch(void* const* d_in, const int* in_sizes, int n_in,
                              void* d_out, int out_size, void* d_ws, size_t ws_size,
                              hipStream_t stream) {
    const float* x = (const float*)d_in[0];
    const int* ei = (const int*)d_in[1];
    const float* W1 = (const float*)d_in[3];
    const float* b1 = (const float*)d_in[4];
    const float* W2 = (const float*)d_in[5];
    const float* b2 = (const float*)d_in[6];
    const float* W3 = (const float*)d_in[7];
    const float* b3 = (const float*)d_in[8];
    const float* W4 = (const float*)d_in[9];
    const float* b4 = (const float*)d_in[10];
    const float* W5 = (const float*)d_in[11];
    const float* b5 = (const float*)d_in[12];
    const float* Wl = (const float*)d_in[13];
    const float* bl = (const float*)d_in[14];

    const int N = in_sizes[0] / 2;
    const int E = in_sizes[1] / 2;
    const int* src = ei;
    const int* dst = ei + E;

    char* wp = (char*)d_ws;
    auto alloc = [&](size_t bytes) -> void* {
        void* p = wp;
        wp += ((bytes + 255) / 256) * 256;
        return p;
    };
    int* cnt = (int*)alloc((size_t)N * 4);
    int* off = (int*)alloc((size_t)(N + 1) * 4);
    int* cursor = (int*)alloc((size_t)N * 4);
    int* bsum = (int*)alloc(512 * 4);
    int* bpre = (int*)alloc(512 * 4);
    int* csr = (int*)alloc((size_t)E * 4);
    float* dinv = (float*)alloc((size_t)N * 4);
    float* xs2 = (float*)alloc((size_t)N * 2 * 4);
    float* t2 = (float*)alloc((size_t)N * 2 * 4);
    float* bufA = (float*)alloc((size_t)N * 128 * 4);
    float* bufB = (float*)alloc((size_t)N * 128 * 4);

    const int gN = cdiv(N, 256);
    const int gE = cdiv(E, 256);
    const int nb = gN;
    const int gT = cdiv(N, 64);
    const int gB = cdiv(N, 128);

    // Ranged fill grid: 8 classes x 128 chunks.
    const int NCHUNK = 128;
    const int echunk = cdiv(E, NCHUNK);
    const int gR = 8 * NCHUNK;

    // --- CSR build ---
    zero_i32<<<gN, 256, 0, stream>>>(cnt, N);
    count_kernel<<<gE, 256, 0, stream>>>(dst, cnt, E);
    scan1<<<nb, 256, 0, stream>>>(cnt, off, bsum, N);
    scan2<<<1, 512, 0, stream>>>(bsum, bpre, nb, off, N, E);
    scan3_fused<<<nb, 256, 0, stream>>>(cnt, bpre, off, cursor, x, dinv, xs2, N);
    fill_ranged<<<gR, 256, 0, stream>>>(src, dst, cursor, csr, E, N, echunk);

    // --- Layer 1: agg pre-scaled [N,2], gemm 2->128 (+b1, relu, *dinv) ---
    agg2_kernel<<<gN, 256, 0, stream>>>(xs2, off, csr, dinv, t2, N);
    gemm_small<2, 128, true, true><<<cdiv(N, 8), 256, 0, stream>>>(t2, W1, b1, dinv, bufA, N);
    // --- Layer 2: gemm_big128 128->128 (raw), agg128 (+b2, relu, *dinv) ---
    gemm_big128<128, false, false><<<gB, 256, 0, stream>>>(bufA, W2, nullptr, nullptr, bufB, N);
    agg128_kernel<true, true><<<cdiv(N, 16), 256, 0, stream>>>(bufB, off, csr, dinv, b2, bufA, N);
    // --- Layer 3: gemm 128->32, agg32 (+b3, relu, *dinv) ---
    gemm_tiled<128, 32, false, false><<<gT, 256, 0, stream>>>(bufA, W3, nullptr, nullptr, bufB, N);
    agg32_kernel<true, true><<<cdiv(N, 32), 256, 0, stream>>>(bufB, off, csr, dinv, b3, bufA, N);
    // --- Layer 4: gemm 32->32, agg32 (+b4, relu, *dinv) ---
    gemm_tiled<32, 32, false, false><<<gT, 256, 0, stream>>>(bufA, W4, nullptr, nullptr, bufB, N);
    agg32_kernel<true, true><<<cdiv(N, 32), 256, 0, stream>>>(bufB, off, csr, dinv, b4, bufA, N);
    // --- Layer 5: agg32 raw -> A_hat x4, fused gemm 32->64 + final 64->1 ---
    agg32_kernel<false, false><<<cdiv(N, 32), 256, 0, stream>>>(bufA, off, csr, dinv, nullptr, bufB, N);
    gemm_final<<<gT, 256, 0, stream>>>(bufB, W5, b5, Wl, bl, (float*)d_out, N);
}

// Round 14
// 557.315 us; speedup vs baseline: 3.8414x; 3.8414x over previous
//
#include <hip/hip_runtime.h>
#include <math.h>

// ---------------------------------------------------------------------------
// GCN 5-layer forward, dinv-prescaled formulation.
//   agg[v] = dinv[v] * ( sum_{s in N(v)} hs[s] + hs[v] ),  hs = dinv (.) h.
// Layer plan (narrow-side aggregation):
//   L1: agg2(xs=dinv*x) -> gemm 2->128 +b1 relu *dinv
//   L2: gemm 128->128 ; agg128 +b2 relu *dinv
//   L3: gemm 128->32  ; agg32  +b3 relu *dinv
//   L4: gemm 32->32   ; agg32  +b4 relu *dinv
//   L5: agg32 raw     ; gemm_final: (t5@W5+b5).relu @ Wl + bl -> out
// R13 post-mortem: gemm_big128 (128x128 tile) — allocator chose 64 VGPR and
//   spilled the 64-reg accumulator file (4.4 GB scratch WRITE, 42ms worst
//   dispatch). REVERTED to R12's gemm_tiled<128,128> (known-good 561us).
// Structural walls (measured): agg128 ~127us (8 XCD x 51 MB compulsory
//   FETCH, invariant across all wave shapes R3-R12); agg32 ~40-45us each;
//   fill/count atomic floors; fp32 vector-ALU gemms (no fp32 MFMA; bf16
//   blows the 7.9e-5 absmax budget).
// ---------------------------------------------------------------------------

static inline int cdiv(int a, int b) { return (a + b - 1) / b; }

__global__ void zero_i32(int* __restrict__ p, int n) {
    int i = blockIdx.x * 256 + threadIdx.x;
    if (i < n) p[i] = 0;
}

// Plain 1-pass degree count: atomics, no line-ownership migration.
__global__ void count_kernel(const int* __restrict__ dst, int* __restrict__ cnt, int E) {
    int e = blockIdx.x * 256 + threadIdx.x;
    if (e < E) atomicAdd(&cnt[dst[e]], 1);
}

// Inclusive scan per 256-block; inclusive partials to off, block totals to bsum.
__global__ void scan1(const int* __restrict__ cnt, int* __restrict__ off,
                      int* __restrict__ bsum, int n) {
    __shared__ int sm[256];
    int i = blockIdx.x * 256 + threadIdx.x;
    int v = (i < n) ? cnt[i] : 0;
    sm[threadIdx.x] = v;
    __syncthreads();
    for (int ofs = 1; ofs < 256; ofs <<= 1) {
        int t = (threadIdx.x >= (unsigned)ofs) ? sm[threadIdx.x - ofs] : 0;
        __syncthreads();
        sm[threadIdx.x] += t;
        __syncthreads();
    }
    if (i < n) off[i] = sm[threadIdx.x];
    if (threadIdx.x == 255) bsum[blockIdx.x] = sm[255];
}

// Exclusive scan of block sums (nb <= 512).
__global__ void scan2(const int* __restrict__ bsum, int* __restrict__ bpre,
                      int nb, int* __restrict__ off, int N, int E) {
    __shared__ int sm[512];
    int t = threadIdx.x;
    sm[t] = (t < nb) ? bsum[t] : 0;
    __syncthreads();
    for (int ofs = 1; ofs < 512; ofs <<= 1) {
        int v = (t >= ofs) ? sm[t - ofs] : 0;
        __syncthreads();
        sm[t] += v;
        __syncthreads();
    }
    if (t < nb) bpre[t] = sm[t] - bsum[t];
    if (t == 0) off[N] = E;
}

// Fused: finalize off (exclusive), seed cursor=off, dinv=1/sqrt(deg+1),
// xs = dinv * x (pre-scaled layer-1 input).
__global__ void scan3_fused(const int* __restrict__ cnt, const int* __restrict__ bpre,
                            int* __restrict__ off, int* __restrict__ cursor,
                            const float* __restrict__ x, float* __restrict__ dinv,
                            float* __restrict__ xs, int n) {
    int i = blockIdx.x * 256 + threadIdx.x;
    if (i < n) {
        int c = cnt[i];
        int o = off[i] - c + bpre[blockIdx.x];
        off[i] = o;
        cursor[i] = o;
        float dv = 1.0f / sqrtf((float)c + 1.0f);
        dinv[i] = dv;
        float2 xv = *reinterpret_cast<const float2*>(x + 2 * (size_t)i);
        *reinterpret_cast<float2*>(xs + 2 * (size_t)i) = float2{dv * xv.x, dv * xv.y};
    }
}

// XCD-class-filtered CSR fill: class c handles only its dst-range, so its
// cursor slice (~50 KB) and csr slice (~800 KB) stay in one XCD's L2.
// (Stores DO need single-writer-XCD locality; see R8.)
__global__ __launch_bounds__(256) void fill_ranged(const int* __restrict__ src,
                                                   const int* __restrict__ dst,
                                                   int* __restrict__ cursor,
                                                   int* __restrict__ csr,
                                                   int E, int N, int echunk) {
    int cls = blockIdx.x & 7;
    int chunk = blockIdx.x >> 3;
    int per = (N + 7) >> 3;
    int lo = cls * per;
    int hi = lo + per; if (hi > N) hi = N;
    int e0 = chunk * echunk;
    int e1 = e0 + echunk; if (e1 > E) e1 = E;
    for (int e = e0 + (int)threadIdx.x; e < e1; e += 256) {
        int d = dst[e];
        if (d >= lo && d < hi) {
            int p = atomicAdd(&cursor[d], 1);
            csr[p] = src[e];
        }
    }
}

// ---------------------------------------------------------------------------
// Aggregation of pre-scaled [N,2] input: one thread per node.
// ---------------------------------------------------------------------------
__global__ __launch_bounds__(256) void agg2_kernel(const float* __restrict__ xs,
                                                   const int* __restrict__ off,
                                                   const int* __restrict__ csr,
                                                   const float* __restrict__ dinv,
                                                   float* __restrict__ out, int n) {
    int v = blockIdx.x * 256 + threadIdx.x;
    if (v >= n) return;
    float a0 = 0.f, a1 = 0.f;
    int e0 = off[v], e1 = off[v + 1];
    for (int e = e0; e < e1; e++) {
        int s = csr[e];
        float2 q = *reinterpret_cast<const float2*>(xs + 2 * (size_t)s);
        a0 += q.x;
        a1 += q.y;
    }
    float dv = dinv[v];
    float2 xv = *reinterpret_cast<const float2*>(xs + 2 * (size_t)v);
    *reinterpret_cast<float2*>(out + 2 * (size_t)v) =
        float2{dv * (a0 + xv.x), dv * (a1 + xv.y)};
}

// ---------------------------------------------------------------------------
// agg128: F=128, 16 lanes/node, each lane owns 8 cols (2 x float4).
// ---------------------------------------------------------------------------
template <bool BR, bool PS>
__global__ __launch_bounds__(256) void agg128_kernel(const float* __restrict__ h,
                                                     const int* __restrict__ off,
                                                     const int* __restrict__ csr,
                                                     const float* __restrict__ dinv,
                                                     const float* __restrict__ bias,
                                                     float* __restrict__ out, int n) {
    int tid = threadIdx.x;
    int lane = tid & 63;
    int sl = lane & 15;
    int subbase = lane & ~15;
    int wave = tid >> 6;
    int v = blockIdx.x * 16 + wave * 4 + (lane >> 4);
    if (v >= n) return;

    int start = off[v];
    int end = off[v + 1];

    float4 accA = {0.f, 0.f, 0.f, 0.f};
    float4 accB = {0.f, 0.f, 0.f, 0.f};

    for (int base = start; base < end; base += 16) {
        int m = end - base;
        if (m > 16) m = 16;
        int idx = (sl < m) ? csr[base + sl] : 0;
        int i = 0;
        for (; i + 8 <= m; i += 8) {
            float4 ha[8], hb[8];
#pragma unroll
            for (int u = 0; u < 8; u++) {
                int s = __shfl(idx, subbase + i + u);
                const float* p = h + (size_t)s * 128 + sl * 8;
                ha[u] = *reinterpret_cast<const float4*>(p);
                hb[u] = *reinterpret_cast<const float4*>(p + 4);
            }
#pragma unroll
            for (int u = 0; u < 8; u++) {
                accA.x += ha[u].x; accA.y += ha[u].y; accA.z += ha[u].z; accA.w += ha[u].w;
                accB.x += hb[u].x; accB.y += hb[u].y; accB.z += hb[u].z; accB.w += hb[u].w;
            }
        }
        if (i + 4 <= m) {
            float4 ha[4], hb[4];
#pragma unroll
            for (int u = 0; u < 4; u++) {
                int s = __shfl(idx, subbase + i + u);
                const float* p = h + (size_t)s * 128 + sl * 8;
                ha[u] = *reinterpret_cast<const float4*>(p);
                hb[u] = *reinterpret_cast<const float4*>(p + 4);
            }
#pragma unroll
            for (int u = 0; u < 4; u++) {
                accA.x += ha[u].x; accA.y += ha[u].y; accA.z += ha[u].z; accA.w += ha[u].w;
                accB.x += hb[u].x; accB.y += hb[u].y; accB.z += hb[u].z; accB.w += hb[u].w;
            }
            i += 4;
        }
        if (i + 2 <= m) {
            int s0 = __shfl(idx, subbase + i);
            int s1 = __shfl(idx, subbase + i + 1);
            const float* p0 = h + (size_t)s0 * 128 + sl * 8;
            const float* p1 = h + (size_t)s1 * 128 + sl * 8;
            float4 a0 = *reinterpret_cast<const float4*>(p0);
            float4 b0 = *reinterpret_cast<const float4*>(p0 + 4);
            float4 a1 = *reinterpret_cast<const float4*>(p1);
            float4 b1 = *reinterpret_cast<const float4*>(p1 + 4);
            accA.x += a0.x + a1.x; accA.y += a0.y + a1.y;
            accA.z += a0.z + a1.z; accA.w += a0.w + a1.w;
            accB.x += b0.x + b1.x; accB.y += b0.y + b1.y;
            accB.z += b0.z + b1.z; accB.w += b0.w + b1.w;
            i += 2;
        }
        if (i < m) {
            int s0 = __shfl(idx, subbase + i);
            const float* p0 = h + (size_t)s0 * 128 + sl * 8;
            float4 a0 = *reinterpret_cast<const float4*>(p0);
            float4 b0 = *reinterpret_cast<const float4*>(p0 + 4);
            accA.x += a0.x; accA.y += a0.y; accA.z += a0.z; accA.w += a0.w;
            accB.x += b0.x; accB.y += b0.y; accB.z += b0.z; accB.w += b0.w;
        }
    }

    float dv = dinv[v];
    const float* pv = h + (size_t)v * 128 + sl * 8;
    float4 hvA = *reinterpret_cast<const float4*>(pv);
    float4 hvB = *reinterpret_cast<const float4*>(pv + 4);
    float4 oA, oB;
    oA.x = dv * (accA.x + hvA.x); oA.y = dv * (accA.y + hvA.y);
    oA.z = dv * (accA.z + hvA.z); oA.w = dv * (accA.w + hvA.w);
    oB.x = dv * (accB.x + hvB.x); oB.y = dv * (accB.y + hvB.y);
    oB.z = dv * (accB.z + hvB.z); oB.w = dv * (accB.w + hvB.w);
    if constexpr (BR) {
        float4 bA = *reinterpret_cast<const float4*>(bias + sl * 8);
        float4 bB = *reinterpret_cast<const float4*>(bias + sl * 8 + 4);
        oA.x = fmaxf(oA.x + bA.x, 0.f); oA.y = fmaxf(oA.y + bA.y, 0.f);
        oA.z = fmaxf(oA.z + bA.z, 0.f); oA.w = fmaxf(oA.w + bA.w, 0.f);
        oB.x = fmaxf(oB.x + bB.x, 0.f); oB.y = fmaxf(oB.y + bB.y, 0.f);
        oB.z = fmaxf(oB.z + bB.z, 0.f); oB.w = fmaxf(oB.w + bB.w, 0.f);
    }
    if constexpr (PS) {
        oA.x *= dv; oA.y *= dv; oA.z *= dv; oA.w *= dv;
        oB.x *= dv; oB.y *= dv; oB.z *= dv; oB.w *= dv;
    }
    float* po = out + (size_t)v * 128 + sl * 8;
    *reinterpret_cast<float4*>(po) = oA;
    *reinterpret_cast<float4*>(po + 4) = oB;
}

// ---------------------------------------------------------------------------
// agg32: F=32, 8 lanes/node, lane owns 4 cols (float4). Dual 8-edge chunks.
// ---------------------------------------------------------------------------
template <bool BR, bool PS>
__global__ __launch_bounds__(256) void agg32_kernel(const float* __restrict__ h,
                                                    const int* __restrict__ off,
                                                    const int* __restrict__ csr,
                                                    const float* __restrict__ dinv,
                                                    const float* __restrict__ bias,
                                                    float* __restrict__ out, int n) {
    int tid = threadIdx.x;
    int lane = tid & 63;
    int sl = lane & 7;
    int subbase = lane & ~7;
    int wave = tid >> 6;
    int v = blockIdx.x * 32 + wave * 8 + (lane >> 3);
    if (v >= n) return;

    int start = off[v];
    int end = off[v + 1];

    float4 acc = {0.f, 0.f, 0.f, 0.f};

    for (int base = start; base < end; base += 16) {
        int m = end - base;
        if (m > 16) m = 16;
        int idxA = (sl < m) ? csr[base + sl] : 0;
        int idxB = (8 + sl < m) ? csr[base + 8 + sl] : 0;
        if (m == 16) {
            float4 hb[16];
#pragma unroll
            for (int u = 0; u < 16; u++) {
                int s = __shfl((u < 8) ? idxA : idxB, subbase + (u & 7));
                hb[u] = *reinterpret_cast<const float4*>(h + (size_t)s * 32 + sl * 4);
            }
#pragma unroll
            for (int u = 0; u < 16; u++) {
                acc.x += hb[u].x; acc.y += hb[u].y; acc.z += hb[u].z; acc.w += hb[u].w;
            }
        } else {
            int ma = (m < 8) ? m : 8;
            int i = 0;
            for (; i + 4 <= ma; i += 4) {
                float4 hb[4];
#pragma unroll
                for (int u = 0; u < 4; u++) {
                    int s = __shfl(idxA, subbase + i + u);
                    hb[u] = *reinterpret_cast<const float4*>(h + (size_t)s * 32 + sl * 4);
                }
#pragma unroll
                for (int u = 0; u < 4; u++) {
                    acc.x += hb[u].x; acc.y += hb[u].y; acc.z += hb[u].z; acc.w += hb[u].w;
                }
            }
            if (i + 2 <= ma) {
                int s0 = __shfl(idxA, subbase + i);
                int s1 = __shfl(idxA, subbase + i + 1);
                float4 h0 = *reinterpret_cast<const float4*>(h + (size_t)s0 * 32 + sl * 4);
                float4 h1 = *reinterpret_cast<const float4*>(h + (size_t)s1 * 32 + sl * 4);
                acc.x += h0.x + h1.x; acc.y += h0.y + h1.y;
                acc.z += h0.z + h1.z; acc.w += h0.w + h1.w;
                i += 2;
            }
            if (i < ma) {
                int s0 = __shfl(idxA, subbase + i);
                float4 h0 = *reinterpret_cast<const float4*>(h + (size_t)s0 * 32 + sl * 4);
                acc.x += h0.x; acc.y += h0.y; acc.z += h0.z; acc.w += h0.w;
            }
            if (m > 8) {
                int mb = m - 8;
                int j = 0;
                for (; j + 4 <= mb; j += 4) {
                    float4 hb[4];
#pragma unroll
                    for (int u = 0; u < 4; u++) {
                        int s = __shfl(idxB, subbase + j + u);
                        hb[u] = *reinterpret_cast<const float4*>(h + (size_t)s * 32 + sl * 4);
                    }
#pragma unroll
                    for (int u = 0; u < 4; u++) {
                        acc.x += hb[u].x; acc.y += hb[u].y; acc.z += hb[u].z; acc.w += hb[u].w;
                    }
                }
                if (j + 2 <= mb) {
                    int s0 = __shfl(idxB, subbase + j);
                    int s1 = __shfl(idxB, subbase + j + 1);
                    float4 h0 = *reinterpret_cast<const float4*>(h + (size_t)s0 * 32 + sl * 4);
                    float4 h1 = *reinterpret_cast<const float4*>(h + (size_t)s1 * 32 + sl * 4);
                    acc.x += h0.x + h1.x; acc.y += h0.y + h1.y;
                    acc.z += h0.z + h1.z; acc.w += h0.w + h1.w;
                    j += 2;
                }
                if (j < mb) {
                    int s0 = __shfl(idxB, subbase + j);
                    float4 h0 = *reinterpret_cast<const float4*>(h + (size_t)s0 * 32 + sl * 4);
                    acc.x += h0.x; acc.y += h0.y; acc.z += h0.z; acc.w += h0.w;
                }
            }
        }
    }

    float dv = dinv[v];
    float4 hv = *reinterpret_cast<const float4*>(h + (size_t)v * 32 + sl * 4);
    float o0 = dv * (acc.x + hv.x);
    float o1 = dv * (acc.y + hv.y);
    float o2 = dv * (acc.z + hv.z);
    float o3 = dv * (acc.w + hv.w);
    if constexpr (BR) {
        float4 b = *reinterpret_cast<const float4*>(bias + sl * 4);
        o0 = fmaxf(o0 + b.x, 0.f);
        o1 = fmaxf(o1 + b.y, 0.f);
        o2 = fmaxf(o2 + b.z, 0.f);
        o3 = fmaxf(o3 + b.w, 0.f);
    }
    if constexpr (PS) {
        o0 *= dv; o1 *= dv; o2 *= dv; o3 *= dv;
    }
    *reinterpret_cast<float4*>(out + (size_t)v * 32 + sl * 4) = float4{o0, o1, o2, o3};
}

// ---------------------------------------------------------------------------
// Register-tiled GEMM: h[N,F] = x[N,K] @ W[K,F]; epilogue +bias/relu (BR),
// *dinv[row] (PS). KC=32 (KCP=36 breaks pow-2 banks): K=128 -> 4 chunks,
// K=32 -> single chunk (2 barriers).
// ---------------------------------------------------------------------------
template <int K, int F, bool BR, bool PS>
__global__ __launch_bounds__(256, 4) void gemm_tiled(const float* __restrict__ x,
                                                     const float* __restrict__ W,
                                                     const float* __restrict__ bias,
                                                     const float* __restrict__ dinv,
                                                     float* __restrict__ h, int n) {
    constexpr int KC = 32;
    constexpr int KCP = 36;             // padded row stride (144 B, 16B-aligned)
    constexpr int ROWS = 64;
    constexpr int TPC = F / 4;
    constexpr int RT = 256 / TPC;
    constexpr int RPT = ROWS / RT;
    static_assert(K % KC == 0, "K must be a multiple of 32");

    __shared__ float Ws[KC * F];
    __shared__ float Xs[ROWS * KCP];

    const int tid = threadIdx.x;
    const int cb = (tid % TPC) * 4;
    const int tr = tid / TPC;
    const int row0 = blockIdx.x * ROWS;

    float acc[RPT][4];
#pragma unroll
    for (int r = 0; r < RPT; r++)
#pragma unroll
        for (int j = 0; j < 4; j++) acc[r][j] = 0.f;

#pragma unroll 1
    for (int k0 = 0; k0 < K; k0 += KC) {
        __syncthreads();
        {
            // Stage x chunk: 64 rows x 32 cols; thread -> row tid>>2, 8 cols.
            int r = tid >> 2;
            int kk = (tid & 3) * 8;
            int gr = row0 + r;
            float4 v0 = {0.f, 0.f, 0.f, 0.f}, v1 = {0.f, 0.f, 0.f, 0.f};
            if (gr < n) {
                v0 = *reinterpret_cast<const float4*>(x + (size_t)gr * K + k0 + kk);
                v1 = *reinterpret_cast<const float4*>(x + (size_t)gr * K + k0 + kk + 4);
            }
            *reinterpret_cast<float4*>(&Xs[r * KCP + kk]) = v0;
            *reinterpret_cast<float4*>(&Xs[r * KCP + kk + 4]) = v1;
        }
        for (int i = tid; i < KC * F / 4; i += 256) {
            *reinterpret_cast<float4*>(&Ws[i * 4]) =
                *reinterpret_cast<const float4*>(W + (size_t)k0 * F + i * 4);
        }
        __syncthreads();

#pragma unroll 4
        for (int kk4 = 0; kk4 < KC; kk4 += 4) {
            float4 xr[RPT];
#pragma unroll
            for (int r = 0; r < RPT; r++)
                xr[r] = *reinterpret_cast<const float4*>(&Xs[(tr * RPT + r) * KCP + kk4]);
#pragma unroll
            for (int j = 0; j < 4; j++) {
                float4 w = *reinterpret_cast<const float4*>(&Ws[(kk4 + j) * F + cb]);
#pragma unroll
                for (int r = 0; r < RPT; r++) {
                    float xv = (j == 0) ? xr[r].x : (j == 1) ? xr[r].y
                             : (j == 2) ? xr[r].z : xr[r].w;
                    acc[r][0] += xv * w.x;
                    acc[r][1] += xv * w.y;
                    acc[r][2] += xv * w.z;
                    acc[r][3] += xv * w.w;
                }
            }
        }
    }

    float4 b = float4{0.f, 0.f, 0.f, 0.f};
    if constexpr (BR) b = *reinterpret_cast<const float4*>(bias + cb);
#pragma unroll
    for (int r = 0; r < RPT; r++) {
        int row = row0 + tr * RPT + r;
        if (row < n) {
            float o0 = acc[r][0], o1 = acc[r][1], o2 = acc[r][2], o3 = acc[r][3];
            if constexpr (BR) {
                o0 = fmaxf(o0 + b.x, 0.f);
                o1 = fmaxf(o1 + b.y, 0.f);
                o2 = fmaxf(o2 + b.z, 0.f);
                o3 = fmaxf(o3 + b.w, 0.f);
            }
            if constexpr (PS) {
                float dv = dinv[row];
                o0 *= dv; o1 *= dv; o2 *= dv; o3 *= dv;
            }
            *reinterpret_cast<float4*>(&h[(size_t)row * F + cb]) = float4{o0, o1, o2, o3};
        }
    }
}

// ---------------------------------------------------------------------------
// Fused L5 + final: out[v] = relu(t5[v]@W5 + b5) . Wl + bl.  K=32, F=64.
// Single KC=32 chunk; row outputs in 16 lanes x 4 regs -> dot with Wl (LDS)
// then 4-step shfl-xor reduce; lane0-of-16 writes out[row].
// ---------------------------------------------------------------------------
__global__ __launch_bounds__(256, 4) void gemm_final(const float* __restrict__ x,
                                                     const float* __restrict__ W,
                                                     const float* __restrict__ bias,
                                                     const float* __restrict__ Wl,
                                                     const float* __restrict__ bl,
                                                     float* __restrict__ out, int n) {
    constexpr int K = 32, F = 64;
    constexpr int KC = 32;
    constexpr int KCP = 36;
    constexpr int ROWS = 64;
    constexpr int TPC = F / 4;          // 16
    constexpr int RT = 256 / TPC;       // 16
    constexpr int RPT = ROWS / RT;      // 4

    __shared__ float Ws[KC * F];
    __shared__ float Xs[ROWS * KCP];
    __shared__ float wl[F];

    const int tid = threadIdx.x;
    if (tid < F) wl[tid] = Wl[tid];
    const int cb = (tid % TPC) * 4;
    const int tr = tid / TPC;
    const int row0 = blockIdx.x * ROWS;

    float acc[RPT][4];
#pragma unroll
    for (int r = 0; r < RPT; r++)
#pragma unroll
        for (int j = 0; j < 4; j++) acc[r][j] = 0.f;

    {
        {
            int r = tid >> 2;
            int kk = (tid & 3) * 8;
            int gr = row0 + r;
            float4 v0 = {0.f, 0.f, 0.f, 0.f}, v1 = {0.f, 0.f, 0.f, 0.f};
            if (gr < n) {
                v0 = *reinterpret_cast<const float4*>(x + (size_t)gr * K + kk);
                v1 = *reinterpret_cast<const float4*>(x + (size_t)gr * K + kk + 4);
            }
            *reinterpret_cast<float4*>(&Xs[r * KCP + kk]) = v0;
            *reinterpret_cast<float4*>(&Xs[r * KCP + kk + 4]) = v1;
        }
        for (int i = tid; i < KC * F / 4; i += 256) {
            *reinterpret_cast<float4*>(&Ws[i * 4]) =
                *reinterpret_cast<const float4*>(W + i * 4);
        }
        __syncthreads();

#pragma unroll 4
        for (int kk4 = 0; kk4 < KC; kk4 += 4) {
            float4 xr[RPT];
#pragma unroll
            for (int r = 0; r < RPT; r++)
                xr[r] = *reinterpret_cast<const float4*>(&Xs[(tr * RPT + r) * KCP + kk4]);
#pragma unroll
            for (int j = 0; j < 4; j++) {
                float4 w = *reinterpret_cast<const float4*>(&Ws[(kk4 + j) * F + cb]);
#pragma unroll
                for (int r = 0; r < RPT; r++) {
                    float xv = (j == 0) ? xr[r].x : (j == 1) ? xr[r].y
                             : (j == 2) ? xr[r].z : xr[r].w;
                    acc[r][0] += xv * w.x;
                    acc[r][1] += xv * w.y;
                    acc[r][2] += xv * w.z;
                    acc[r][3] += xv * w.w;
                }
            }
        }
    }

    float4 b = *reinterpret_cast<const float4*>(bias + cb);
    float4 w = *reinterpret_cast<const float4*>(&wl[cb]);
    float blv = bl[0];
#pragma unroll
    for (int r = 0; r < RPT; r++) {
        int row = row0 + tr * RPT + r;
        float o0 = fmaxf(acc[r][0] + b.x, 0.f);
        float o1 = fmaxf(acc[r][1] + b.y, 0.f);
        float o2 = fmaxf(acc[r][2] + b.z, 0.f);
        float o3 = fmaxf(acc[r][3] + b.w, 0.f);
        float partial = o0 * w.x + o1 * w.y + o2 * w.z + o3 * w.w;
        partial += __shfl_xor(partial, 8, 16);
        partial += __shfl_xor(partial, 4, 16);
        partial += __shfl_xor(partial, 2, 16);
        partial += __shfl_xor(partial, 1, 16);
        if ((tid & 15) == 0 && row < n) out[row] = partial + blv;
    }
}

// Simple GEMM for K=2 (layer 1), epilogue +bias/relu (BR), *dinv (PS).
template <int K, int F, bool BR, bool PS>
__global__ __launch_bounds__(256, 4) void gemm_small(const float* __restrict__ x,
                                                     const float* __restrict__ W,
                                                     const float* __restrict__ bias,
                                                     const float* __restrict__ dinv,
                                                     float* __restrict__ h, int n) {
    constexpr int TPR = F / 4;
    constexpr int ROWS = 256 / TPR;
    __shared__ float Ws[K * F];
    for (int i = threadIdx.x; i < K * F; i += 256) Ws[i] = W[i];
    __syncthreads();

    int tid = threadIdx.x;
    int cb = (tid % TPR) * 4;
    int r = blockIdx.x * ROWS + tid / TPR;
    if (r >= n) return;

    const float* xr = x + (size_t)r * K;
    float a0 = 0.f, a1 = 0.f, a2 = 0.f, a3 = 0.f;
#pragma unroll
    for (int k = 0; k < K; k++) {
        float xv = xr[k];
        float4 w = *reinterpret_cast<const float4*>(&Ws[k * F + cb]);
        a0 += xv * w.x; a1 += xv * w.y; a2 += xv * w.z; a3 += xv * w.w;
    }
    if constexpr (BR) {
        float4 b = *reinterpret_cast<const float4*>(bias + cb);
        a0 = fmaxf(a0 + b.x, 0.f);
        a1 = fmaxf(a1 + b.y, 0.f);
        a2 = fmaxf(a2 + b.z, 0.f);
        a3 = fmaxf(a3 + b.w, 0.f);
    }
    if constexpr (PS) {
        float dv = dinv[r];
        a0 *= dv; a1 *= dv; a2 *= dv; a3 *= dv;
    }
    *reinterpret_cast<float4*>(&h[(size_t)r * F + cb]) = float4{a0, a1, a2, a3};
}

extern "C" void kernel_launch(void* const* d_in, const int* in_sizes, int n_in,
                              void* d_out, int out_size, void* d_ws, size_t ws_size,
                              hipStream_t stream) {
    const float* x = (const float*)d_in[0];
    const int* ei = (const int*)d_in[1];
    const float* W1 = (const float*)d_in[3];
    const float* b1 = (const float*)d_in[4];
    const float* W2 = (const float*)d_in[5];
    const float* b2 = (const float*)d_in[6];
    const float* W3 = (const float*)d_in[7];
    const float* b3 = (const float*)d_in[8];
    const float* W4 = (const float*)d_in[9];
    const float* b4 = (const float*)d_in[10];
    const float* W5 = (const float*)d_in[11];
    const float* b5 = (const float*)d_in[12];
    const float* Wl = (const float*)d_in[13];
    const float* bl = (const float*)d_in[14];

    const int N = in_sizes[0] / 2;
    const int E = in_sizes[1] / 2;
    const int* src = ei;
    const int* dst = ei + E;

    char* wp = (char*)d_ws;
    auto alloc = [&](size_t bytes) -> void* {
        void* p = wp;
        wp += ((bytes + 255) / 256) * 256;
        return p;
    };
    int* cnt = (int*)alloc((size_t)N * 4);
    int* off = (int*)alloc((size_t)(N + 1) * 4);
    int* cursor = (int*)alloc((size_t)N * 4);
    int* bsum = (int*)alloc(512 * 4);
    int* bpre = (int*)alloc(512 * 4);
    int* csr = (int*)alloc((size_t)E * 4);
    float* dinv = (float*)alloc((size_t)N * 4);
    float* xs2 = (float*)alloc((size_t)N * 2 * 4);
    float* t2 = (float*)alloc((size_t)N * 2 * 4);
    float* bufA = (float*)alloc((size_t)N * 128 * 4);
    float* bufB = (float*)alloc((size_t)N * 128 * 4);

    const int gN = cdiv(N, 256);
    const int gE = cdiv(E, 256);
    const int nb = gN;
    const int gT = cdiv(N, 64);

    // Ranged fill grid: 8 classes x 128 chunks.
    const int NCHUNK = 128;
    const int echunk = cdiv(E, NCHUNK);
    const int gR = 8 * NCHUNK;

    // --- CSR build ---
    zero_i32<<<gN, 256, 0, stream>>>(cnt, N);
    count_kernel<<<gE, 256, 0, stream>>>(dst, cnt, E);
    scan1<<<nb, 256, 0, stream>>>(cnt, off, bsum, N);
    scan2<<<1, 512, 0, stream>>>(bsum, bpre, nb, off, N, E);
    scan3_fused<<<nb, 256, 0, stream>>>(cnt, bpre, off, cursor, x, dinv, xs2, N);
    fill_ranged<<<gR, 256, 0, stream>>>(src, dst, cursor, csr, E, N, echunk);

    // --- Layer 1: agg pre-scaled [N,2], gemm 2->128 (+b1, relu, *dinv) ---
    agg2_kernel<<<gN, 256, 0, stream>>>(xs2, off, csr, dinv, t2, N);
    gemm_small<2, 128, true, true><<<cdiv(N, 8), 256, 0, stream>>>(t2, W1, b1, dinv, bufA, N);
    // --- Layer 2: gemm 128->128 (raw), agg128 (+b2, relu, *dinv) ---
    gemm_tiled<128, 128, false, false><<<gT, 256, 0, stream>>>(bufA, W2, nullptr, nullptr, bufB, N);
    agg128_kernel<true, true><<<cdiv(N, 16), 256, 0, stream>>>(bufB, off, csr, dinv, b2, bufA, N);
    // --- Layer 3: gemm 128->32, agg32 (+b3, relu, *dinv) ---
    gemm_tiled<128, 32, false, false><<<gT, 256, 0, stream>>>(bufA, W3, nullptr, nullptr, bufB, N);
    agg32_kernel<true, true><<<cdiv(N, 32), 256, 0, stream>>>(bufB, off, csr, dinv, b3, bufA, N);
    // --- Layer 4: gemm 32->32, agg32 (+b4, relu, *dinv) ---
    gemm_tiled<32, 32, false, false><<<gT, 256, 0, stream>>>(bufA, W4, nullptr, nullptr, bufB, N);
    agg32_kernel<true, true><<<cdiv(N, 32), 256, 0, stream>>>(bufB, off, csr, dinv, b4, bufA, N);
    // --- Layer 5: agg32 raw -> A_hat x4, fused gemm 32->64 + final 64->1 ---
    agg32_kernel<false, false><<<cdiv(N, 32), 256, 0, stream>>>(bufA, off, csr, dinv, nullptr, bufB, N);
    gemm_final<<<gT, 256, 0, stream>>>(bufB, W5, b5, Wl, bl, (float*)d_out, N);
}